// Round 2
// baseline (655.306 us; speedup 1.0000x reference)
//
#include <hip/hip_runtime.h>
#include <hip/hip_bf16.h>
#include <math.h>

typedef __bf16 bf16_t;
typedef __bf16 bf16x4 __attribute__((ext_vector_type(4)));
typedef short  s16x8  __attribute__((ext_vector_type(8)));
typedef float  f32x4  __attribute__((ext_vector_type(4)));

#define DEVINL __device__ __forceinline__

DEVINL void gload_lds16(const void* g, void* l) {
  __builtin_amdgcn_global_load_lds(
      (const __attribute__((address_space(1))) unsigned int*)g,
      (__attribute__((address_space(3))) unsigned int*)l, 16, 0, 0);
}

DEVINL f32x4 mfma16(s16x8 a, s16x8 b, f32x4 c) {
  return __builtin_amdgcn_mfma_f32_16x16x32_bf16(a, b, c, 0, 0, 0);
}

// ---------------- transpose + cast: W[K][N] f32 -> WT[N][K] bf16 ----------------
__global__ __launch_bounds__(256) void tcast_kernel(const float* __restrict__ W,
                                                    bf16_t* __restrict__ WT,
                                                    int K, int N) {
  __shared__ float tile[32][33];
  const int n0 = blockIdx.x * 32, k0 = blockIdx.y * 32;
  const int tx = threadIdx.x, ty = threadIdx.y;
#pragma unroll
  for (int j = 0; j < 4; ++j)
    tile[ty + j * 8][tx] = W[(size_t)(k0 + ty + j * 8) * N + (n0 + tx)];
  __syncthreads();
#pragma unroll
  for (int j = 0; j < 4; ++j)
    WT[(size_t)(n0 + ty + j * 8) * K + (k0 + tx)] = (bf16_t)tile[tx][ty + j * 8];
}

// ---------------- layernorm: f32 [rows][1024] -> bf16 ----------------
__global__ __launch_bounds__(256) void ln_kernel(const float* __restrict__ x,
                                                 const float* __restrict__ w,
                                                 const float* __restrict__ b,
                                                 bf16_t* __restrict__ out) {
  const int row = blockIdx.x, tid = threadIdx.x;
  const float4 v = ((const float4*)(x + (size_t)row * 1024))[tid];
  float s  = v.x + v.y + v.z + v.w;
  float s2 = v.x * v.x + v.y * v.y + v.z * v.z + v.w * v.w;
#pragma unroll
  for (int off = 32; off > 0; off >>= 1) {
    s  += __shfl_down(s, off);
    s2 += __shfl_down(s2, off);
  }
  __shared__ float red[8];
  const int wave = tid >> 6, lane = tid & 63;
  if (lane == 0) { red[wave] = s; red[4 + wave] = s2; }
  __syncthreads();
  s  = red[0] + red[1] + red[2] + red[3];
  s2 = red[4] + red[5] + red[6] + red[7];
  const float mu = s * (1.0f / 1024.0f);
  const float rs = rsqrtf(s2 * (1.0f / 1024.0f) - mu * mu + 1e-5f);
  const float4 wv = ((const float4*)w)[tid];
  const float4 bv = ((const float4*)b)[tid];
  bf16x4 o;
  o[0] = (bf16_t)((v.x - mu) * rs * wv.x + bv.x);
  o[1] = (bf16_t)((v.y - mu) * rs * wv.y + bv.y);
  o[2] = (bf16_t)((v.z - mu) * rs * wv.z + bv.z);
  o[3] = (bf16_t)((v.w - mu) * rs * wv.w + bv.w);
  ((bf16x4*)(out + (size_t)row * 1024))[tid] = o;
}

// ---------------- GEMM: C[M][N] = A[M][K] (bf16) * BT[N][K]^T (bf16) + epi ------
// EPI 0: +bias -> bf16 out
// EPI 1: +bias +resid(f32) -> f32 out
// EPI 2: gelu(+bias) -> bf16 out
template <int EPI>
__global__ __launch_bounds__(256) void gemm128(const bf16_t* __restrict__ A,
                                               const bf16_t* __restrict__ BT,
                                               const float* __restrict__ bias,
                                               const float* __restrict__ resid,
                                               void* __restrict__ out,
                                               int M, int N, int K) {
  __shared__ __align__(16) bf16_t sA[128 * 32];
  __shared__ __align__(16) bf16_t sB[128 * 32];
  const int tid = threadIdx.x;
  const int lane = tid & 63, wave = tid >> 6;
  const int wr = wave >> 1, wc = wave & 1;
  const int g = lane >> 4, lr = lane & 15;
  const int m0 = blockIdx.x * 128, n0 = blockIdx.y * 128;

  f32x4 acc[4][4] = {};

  for (int kt = 0; kt < K; kt += 32) {
    __syncthreads();
#pragma unroll
    for (int p = 0; p < 2; ++p) {
      const int c = p * 256 + wave * 64 + lane;   // 16B chunk id, 512 total
      const int row = c >> 2;                     // 4 chunks per 32-elem row
      const int kk = (c & 3) << 3;
      char* baseA = (char*)sA + (size_t)(p * 256 + wave * 64) * 16;
      char* baseB = (char*)sB + (size_t)(p * 256 + wave * 64) * 16;
      gload_lds16(A + (size_t)(m0 + row) * K + kt + kk, baseA);
      gload_lds16(BT + (size_t)(n0 + row) * K + kt + kk, baseB);
    }
    __syncthreads();
    s16x8 af[4], bfr[4];
#pragma unroll
    for (int m = 0; m < 4; ++m)
      af[m] = *(const s16x8*)&sA[(wr * 64 + m * 16 + lr) * 32 + g * 8];
#pragma unroll
    for (int n = 0; n < 4; ++n)
      bfr[n] = *(const s16x8*)&sB[(wc * 64 + n * 16 + lr) * 32 + g * 8];
#pragma unroll
    for (int m = 0; m < 4; ++m)
#pragma unroll
      for (int n = 0; n < 4; ++n)
        acc[m][n] = mfma16(af[m], bfr[n], acc[m][n]);
  }

#pragma unroll
  for (int m = 0; m < 4; ++m)
#pragma unroll
    for (int n = 0; n < 4; ++n) {
      const int col = n0 + wc * 64 + n * 16 + lr;
      const float bv = bias[col];
#pragma unroll
      for (int i = 0; i < 4; ++i) {
        const int rrow = m0 + wr * 64 + m * 16 + g * 4 + i;
        const size_t idx = (size_t)rrow * N + col;
        float v = acc[m][n][i] + bv;
        if (EPI == 1) {
          v += resid[idx];
          ((float*)out)[idx] = v;
        } else if (EPI == 2) {
          v = 0.5f * v * (1.0f + erff(v * 0.70710678118f));
          ((bf16_t*)out)[idx] = (bf16_t)v;
        } else {
          ((bf16_t*)out)[idx] = (bf16_t)v;
        }
      }
    }
}

// ---------------- flash attention ----------------
// qkv: bf16 [8192][3072]  (q at col 0, k at 1024, v at 2048; head h at h*64)
// O:   bf16 [8192][1024]
__global__ __launch_bounds__(256) void flash_attn(const bf16_t* __restrict__ qkv,
                                                  bf16_t* __restrict__ O) {
  const int S = 2048;
  const int qt = blockIdx.x;   // 32 q-tiles of 64 rows
  const int bh = blockIdx.y;   // 64 (b,h)
  const int b = bh >> 4, h = bh & 15;
  const size_t rowbase = (size_t)b * S;
  const int tid = threadIdx.x, lane = tid & 63, wave = tid >> 6;
  const int g = lane >> 4, lr = lane & 15;
  const int q0w = qt * 64 + wave * 16;

  __shared__ __align__(16) bf16_t sK[64 * 64];       // linear dest, XOR-swizzled content
  __shared__ __align__(16) bf16_t sVT[64 * 72];      // VT[d][kv], pad stride 72
  __shared__ __align__(16) bf16_t sP[4][16 * 72];    // per-wave P, pad stride 72

  // Q fragments (row = lr, k = 8g+i (+32*st)), hoisted out of the KV loop
  s16x8 aq[2];
  {
    const bf16_t* qrow = qkv + (rowbase + q0w + lr) * 3072 + h * 64;
    aq[0] = *(const s16x8*)(qrow + g * 8);
    aq[1] = *(const s16x8*)(qrow + 32 + g * 8);
  }

  f32x4 oa[4] = {};
  float mrun[4], lrun[4];
#pragma unroll
  for (int i = 0; i < 4; ++i) { mrun[i] = -1e30f; lrun[i] = 0.0f; }

  for (int kv0 = 0; kv0 < S; kv0 += 64) {
    __syncthreads();
    // stage K tile: 64 rows x 64 d; XOR-swizzled global source, linear LDS dest
#pragma unroll
    for (int p = 0; p < 2; ++p) {
      const int c = p * 256 + tid;             // 16B chunk, 8 per row
      const int r = c >> 3;
      const int pb = (c & 7) ^ (r & 7);
      char* base = (char*)sK + (size_t)(p * 256 + wave * 64) * 16;
      gload_lds16(qkv + (rowbase + kv0 + r) * 3072 + 1024 + h * 64 + pb * 8, base);
    }
    // stage V transposed: VT[d][kv]
#pragma unroll
    for (int p = 0; p < 2; ++p) {
      const int kv = (tid >> 3) + p * 32;
      const int d0 = (tid & 7) * 8;
      const s16x8 vv = *(const s16x8*)(qkv + (rowbase + kv0 + kv) * 3072 + 2048 + h * 64 + d0);
#pragma unroll
      for (int j = 0; j < 8; ++j)
        sVT[(d0 + j) * 72 + kv] = ((const bf16_t*)&vv)[j];
    }
    __syncthreads();

    // QK^T: S[16 q][64 kv], 4 col-frags x 2 k-steps
    f32x4 sc[4] = {};
#pragma unroll
    for (int st = 0; st < 2; ++st)
#pragma unroll
      for (int fc = 0; fc < 4; ++fc) {
        const int kvr = fc * 16 + lr;
        const int pb = (g + 4 * st) ^ (lr & 7);
        const s16x8 bk = *(const s16x8*)&sK[kvr * 64 + pb * 8];
        sc[fc] = mfma16(aq[st], bk, sc[fc]);
      }

    // online softmax (q-rows g*4+i, spread across 16 lanes lr)
    float rmax[4], mnew[4], alpha[4], rsum[4];
#pragma unroll
    for (int i = 0; i < 4; ++i)
      rmax[i] = fmaxf(fmaxf(sc[0][i], sc[1][i]), fmaxf(sc[2][i], sc[3][i]));
#pragma unroll
    for (int msk = 1; msk < 16; msk <<= 1)
#pragma unroll
      for (int i = 0; i < 4; ++i)
        rmax[i] = fmaxf(rmax[i], __shfl_xor(rmax[i], msk));
#pragma unroll
    for (int i = 0; i < 4; ++i) {
      mnew[i] = fmaxf(mrun[i], rmax[i] * 0.125f);
      alpha[i] = __expf(mrun[i] - mnew[i]);
      mrun[i] = mnew[i];
      rsum[i] = 0.0f;
    }
#pragma unroll
    for (int fc = 0; fc < 4; ++fc)
#pragma unroll
      for (int i = 0; i < 4; ++i) {
        const float pp = __expf(sc[fc][i] * 0.125f - mnew[i]);
        sc[fc][i] = pp;
        rsum[i] += pp;
      }
#pragma unroll
    for (int msk = 1; msk < 16; msk <<= 1)
#pragma unroll
      for (int i = 0; i < 4; ++i) rsum[i] += __shfl_xor(rsum[i], msk);
#pragma unroll
    for (int i = 0; i < 4; ++i) lrun[i] = lrun[i] * alpha[i] + rsum[i];
#pragma unroll
    for (int fc2 = 0; fc2 < 4; ++fc2)
#pragma unroll
      for (int i = 0; i < 4; ++i) oa[fc2][i] *= alpha[i];

    // P: C-layout -> per-wave LDS (no barrier: same-wave in-order) -> A-layout
#pragma unroll
    for (int fc = 0; fc < 4; ++fc)
#pragma unroll
      for (int i = 0; i < 4; ++i)
        sP[wave][(g * 4 + i) * 72 + fc * 16 + lr] = (bf16_t)sc[fc][i];

    // PV: O[16 q][64 d] += P[16][64] @ V[64][64]
#pragma unroll
    for (int st = 0; st < 2; ++st) {
      const s16x8 pa = *(const s16x8*)&sP[wave][lr * 72 + st * 32 + g * 8];
#pragma unroll
      for (int fc2 = 0; fc2 < 4; ++fc2) {
        const s16x8 bv = *(const s16x8*)&sVT[(fc2 * 16 + lr) * 72 + st * 32 + g * 8];
        oa[fc2] = mfma16(pa, bv, oa[fc2]);
      }
    }
  }

#pragma unroll
  for (int fc2 = 0; fc2 < 4; ++fc2)
#pragma unroll
    for (int i = 0; i < 4; ++i) {
      const float v = oa[fc2][i] / lrun[i];
      O[(rowbase + q0w + g * 4 + i) * 1024 + h * 64 + fc2 * 16 + lr] = (bf16_t)v;
    }
}

// ---------------- launch ----------------
extern "C" void kernel_launch(void* const* d_in, const int* in_sizes, int n_in,
                              void* d_out, int out_size, void* d_ws, size_t ws_size,
                              hipStream_t stream) {
  const float* x    = (const float*)d_in[0];
  const float* ln1w = (const float*)d_in[1];
  const float* ln1b = (const float*)d_in[2];
  const float* Wqkv = (const float*)d_in[3];
  const float* bqkv = (const float*)d_in[4];
  const float* Wo   = (const float*)d_in[5];
  const float* bo   = (const float*)d_in[6];
  const float* ln2w = (const float*)d_in[7];
  const float* ln2b = (const float*)d_in[8];
  const float* fc1w = (const float*)d_in[9];
  const float* fc1b = (const float*)d_in[10];
  const float* fc2w = (const float*)d_in[11];
  const float* fc2b = (const float*)d_in[12];

  const int M = 8192;

  char* ws = (char*)d_ws;
  size_t off = 0;
  auto alloc = [&](size_t bytes) {
    char* p = ws + off;
    off += (bytes + 255) & ~(size_t)255;
    return p;
  };
  // persistent-lifetime buffers
  bf16_t* WqkvT = (bf16_t*)alloc((size_t)3072 * 1024 * 2);   // 6 MB
  bf16_t* WoT   = (bf16_t*)alloc((size_t)1024 * 1024 * 2);   // 2 MB
  bf16_t* fc1T  = (bf16_t*)alloc((size_t)4096 * 1024 * 2);   // 8 MB
  bf16_t* fc2T  = (bf16_t*)alloc((size_t)1024 * 4096 * 2);   // 8 MB
  bf16_t* h1    = (bf16_t*)alloc((size_t)M * 1024 * 2);      // 16 MB (reused as h2)
  bf16_t* qkvb  = (bf16_t*)alloc((size_t)M * 3072 * 2);      // 48 MB \ overlaid by gbuf
  bf16_t* attnO = (bf16_t*)alloc((size_t)M * 1024 * 2);      // 16 MB /  (64 MB exactly)
  float*  x2    = (float*)alloc((size_t)M * 1024 * 4);       // 32 MB
  // aliases (lifetimes disjoint in stream order)
  bf16_t* h2   = h1;              // h1 dead after QKV GEMM
  bf16_t* gbuf = qkvb;            // qkvb dead after attn, attnO dead after o-proj
  if (off > ws_size) return;      // ~136 MB required

  const dim3 tb(32, 8);
  tcast_kernel<<<dim3(96, 32), tb, 0, stream>>>(Wqkv, WqkvT, 1024, 3072);
  tcast_kernel<<<dim3(32, 32), tb, 0, stream>>>(Wo, WoT, 1024, 1024);
  tcast_kernel<<<dim3(128, 32), tb, 0, stream>>>(fc1w, fc1T, 1024, 4096);
  tcast_kernel<<<dim3(32, 128), tb, 0, stream>>>(fc2w, fc2T, 4096, 1024);

  ln_kernel<<<M, 256, 0, stream>>>(x, ln1w, ln1b, h1);

  gemm128<0><<<dim3(64, 24), 256, 0, stream>>>(h1, WqkvT, bqkv, nullptr, qkvb, M, 3072, 1024);

  flash_attn<<<dim3(32, 64), 256, 0, stream>>>(qkvb, attnO);

  gemm128<1><<<dim3(64, 8), 256, 0, stream>>>(attnO, WoT, bo, x, x2, M, 1024, 1024);

  ln_kernel<<<M, 256, 0, stream>>>(x2, ln2w, ln2b, h2);

  gemm128<2><<<dim3(64, 32), 256, 0, stream>>>(h2, fc1T, fc1b, nullptr, gbuf, M, 4096, 1024);

  gemm128<1><<<dim3(64, 8), 256, 0, stream>>>(gbuf, fc2T, fc2b, x2, (float*)d_out, M, 1024, 4096);
}

// Round 4
// 484.692 us; speedup vs baseline: 1.3520x; 1.3520x over previous
//
#include <hip/hip_runtime.h>
#include <hip/hip_bf16.h>
#include <math.h>

typedef __bf16 bf16_t;
typedef __bf16 bf16x4 __attribute__((ext_vector_type(4)));
typedef short  s16x8  __attribute__((ext_vector_type(8)));
typedef float  f32x4  __attribute__((ext_vector_type(4)));

#define DEVINL __device__ __forceinline__

DEVINL void gload_lds16(const void* g, void* l) {
  __builtin_amdgcn_global_load_lds(
      (const __attribute__((address_space(1))) unsigned int*)g,
      (__attribute__((address_space(3))) unsigned int*)l, 16, 0, 0);
}

DEVINL f32x4 mfma16(s16x8 a, s16x8 b, f32x4 c) {
  return __builtin_amdgcn_mfma_f32_16x16x32_bf16(a, b, c, 0, 0, 0);
}

// ---------------- transpose + cast: W[K][N] f32 -> WT[N][K] bf16 ----------------
__global__ __launch_bounds__(256) void tcast_kernel(const float* __restrict__ W,
                                                    bf16_t* __restrict__ WT,
                                                    int K, int N) {
  __shared__ float tile[32][33];
  const int n0 = blockIdx.x * 32, k0 = blockIdx.y * 32;
  const int tx = threadIdx.x, ty = threadIdx.y;
#pragma unroll
  for (int j = 0; j < 4; ++j)
    tile[ty + j * 8][tx] = W[(size_t)(k0 + ty + j * 8) * N + (n0 + tx)];
  __syncthreads();
#pragma unroll
  for (int j = 0; j < 4; ++j)
    WT[(size_t)(n0 + ty + j * 8) * K + (k0 + tx)] = (bf16_t)tile[tx][ty + j * 8];
}

// ---------------- layernorm: f32 [rows][1024] -> bf16 ----------------
__global__ __launch_bounds__(256) void ln_kernel(const float* __restrict__ x,
                                                 const float* __restrict__ w,
                                                 const float* __restrict__ b,
                                                 bf16_t* __restrict__ out) {
  const int row = blockIdx.x, tid = threadIdx.x;
  const float4 v = ((const float4*)(x + (size_t)row * 1024))[tid];
  float s  = v.x + v.y + v.z + v.w;
  float s2 = v.x * v.x + v.y * v.y + v.z * v.z + v.w * v.w;
#pragma unroll
  for (int off = 32; off > 0; off >>= 1) {
    s  += __shfl_down(s, off);
    s2 += __shfl_down(s2, off);
  }
  __shared__ float red[8];
  const int wave = tid >> 6, lane = tid & 63;
  if (lane == 0) { red[wave] = s; red[4 + wave] = s2; }
  __syncthreads();
  s  = red[0] + red[1] + red[2] + red[3];
  s2 = red[4] + red[5] + red[6] + red[7];
  const float mu = s * (1.0f / 1024.0f);
  const float rs = rsqrtf(s2 * (1.0f / 1024.0f) - mu * mu + 1e-5f);
  const float4 wv = ((const float4*)w)[tid];
  const float4 bv = ((const float4*)b)[tid];
  bf16x4 o;
  o[0] = (bf16_t)((v.x - mu) * rs * wv.x + bv.x);
  o[1] = (bf16_t)((v.y - mu) * rs * wv.y + bv.y);
  o[2] = (bf16_t)((v.z - mu) * rs * wv.z + bv.z);
  o[3] = (bf16_t)((v.w - mu) * rs * wv.w + bv.w);
  ((bf16x4*)(out + (size_t)row * 1024))[tid] = o;
}

// ---------------- GEMM: C[M][N] = A[M][K] (bf16) * BT[N][K]^T (bf16) + epi ------
// EPI 0: +bias -> bf16 out
// EPI 1: +bias +resid(f32) -> f32 out
// EPI 2: gelu(+bias) -> bf16 out
// EPI 3: qkv split: col<2048 -> bf16 out[M][2048]; col>=2048 -> V^T out2[b][h][d][2048]
template <int EPI>
__global__ __launch_bounds__(256) void gemm128(const bf16_t* __restrict__ A,
                                               const bf16_t* __restrict__ BT,
                                               const float* __restrict__ bias,
                                               const float* __restrict__ resid,
                                               void* __restrict__ out,
                                               void* __restrict__ out2,
                                               int M, int N, int K) {
  __shared__ __align__(16) bf16_t sA[128 * 32];
  __shared__ __align__(16) bf16_t sB[128 * 32];
  const int tid = threadIdx.x;
  const int lane = tid & 63, wave = tid >> 6;
  const int wr = wave >> 1, wc = wave & 1;
  const int g = lane >> 4, lr = lane & 15;
  const int m0 = blockIdx.x * 128, n0 = blockIdx.y * 128;

  f32x4 acc[4][4] = {};

  for (int kt = 0; kt < K; kt += 32) {
    __syncthreads();
#pragma unroll
    for (int p = 0; p < 2; ++p) {
      const int c = p * 256 + wave * 64 + lane;   // 16B chunk id, 512 total
      const int row = c >> 2;                     // 4 chunks per 32-elem row
      const int kk = (c & 3) << 3;
      char* baseA = (char*)sA + (size_t)(p * 256 + wave * 64) * 16;
      char* baseB = (char*)sB + (size_t)(p * 256 + wave * 64) * 16;
      gload_lds16(A + (size_t)(m0 + row) * K + kt + kk, baseA);
      gload_lds16(BT + (size_t)(n0 + row) * K + kt + kk, baseB);
    }
    __syncthreads();
    s16x8 af[4], bfr[4];
#pragma unroll
    for (int m = 0; m < 4; ++m)
      af[m] = *(const s16x8*)&sA[(wr * 64 + m * 16 + lr) * 32 + g * 8];
#pragma unroll
    for (int n = 0; n < 4; ++n)
      bfr[n] = *(const s16x8*)&sB[(wc * 64 + n * 16 + lr) * 32 + g * 8];
#pragma unroll
    for (int m = 0; m < 4; ++m)
#pragma unroll
      for (int n = 0; n < 4; ++n)
        acc[m][n] = mfma16(af[m], bfr[n], acc[m][n]);
  }

#pragma unroll
  for (int m = 0; m < 4; ++m)
#pragma unroll
    for (int n = 0; n < 4; ++n) {
      const int col = n0 + wc * 64 + n * 16 + lr;
      const float bv = bias[col];
      const int rrow0 = m0 + wr * 64 + m * 16 + g * 4;
      if (EPI == 3 && col >= 2048) {
        // V part -> transposed global layout [b][h][d][S], s contiguous
        const int col2 = col - 2048;
        bf16x4 pk;
#pragma unroll
        for (int i = 0; i < 4; ++i) pk[i] = (bf16_t)(acc[m][n][i] + bv);
        const size_t didx =
            ((((size_t)(rrow0 >> 11)) * 16 + (col2 >> 6)) * 64 + (col2 & 63)) * 2048 +
            (rrow0 & 2047);
        *(bf16x4*)&((bf16_t*)out2)[didx] = pk;
      } else {
#pragma unroll
        for (int i = 0; i < 4; ++i) {
          const int rrow = rrow0 + i;
          float v = acc[m][n][i] + bv;
          if (EPI == 1) {
            const size_t idx = (size_t)rrow * N + col;
            v += resid[idx];
            ((float*)out)[idx] = v;
          } else if (EPI == 2) {
            v = 0.5f * v * (1.0f + erff(v * 0.70710678118f));
            ((bf16_t*)out)[(size_t)rrow * N + col] = (bf16_t)v;
          } else if (EPI == 3) {
            ((bf16_t*)out)[(size_t)rrow * 2048 + col] = (bf16_t)v;
          } else {
            ((bf16_t*)out)[(size_t)rrow * N + col] = (bf16_t)v;
          }
        }
      }
    }
}

// ---------------- flash attention (swapped QK^T, staged K & V^T) ----------------
// qk:  bf16 [8192][2048]  (q at col 0, k at col 1024; head h at h*64)
// vt:  bf16 [64 bh][64 d][2048 s]
// O:   bf16 [8192][1024]
__global__ __launch_bounds__(256) void flash_attn2(const bf16_t* __restrict__ qk,
                                                   const bf16_t* __restrict__ vt,
                                                   bf16_t* __restrict__ O) {
  const int S = 2048;
  const int qt = blockIdx.x;   // 32 q-tiles of 64 rows
  const int bh = blockIdx.y;   // 64 (b,h)
  const int h = bh & 15;
  const size_t rowbase = (size_t)(bh >> 4) * S;
  const int tid = threadIdx.x, lane = tid & 63, wave = tid >> 6;
  const int g = lane >> 4, lr = lane & 15;
  const int q0w = qt * 64 + wave * 16;

  __shared__ __align__(16) bf16_t sK[64 * 64];    // [kv][d], XOR-swizzled chunks
  __shared__ __align__(16) bf16_t sVT[64 * 64];   // [d][kv], XOR-swizzled chunks
  __shared__ __align__(16) bf16_t sP[4][16 * 72]; // per-wave P[q][kv], pad 72

  const bf16_t* vtb = vt + (size_t)bh * 64 * 2048;

  // Q fragments: lane (g,lr) holds Q[q=lr][k=8g+j (+32*st)]
  s16x8 aq[2];
  {
    const bf16_t* qrow = qk + (rowbase + q0w + lr) * 2048 + h * 64;
    aq[0] = *(const s16x8*)(qrow + g * 8);
    aq[1] = *(const s16x8*)(qrow + 32 + g * 8);
  }

  f32x4 oa[4] = {};               // O^T[d = f2*16+4g+i][q = lr]
  float mrun = -1e30f, lrun = 0.0f;

  for (int kv0 = 0; kv0 < S; kv0 += 64) {
    __syncthreads();
    // stage K [64 kv][64 d] and VT [64 d][64 kv]; swizzled source, linear dest
#pragma unroll
    for (int p = 0; p < 2; ++p) {
      const int c = p * 256 + wave * 64 + lane;  // 16B chunk, 8 per row
      const int r = c >> 3;
      const int pb = (c & 7) ^ (r & 7);
      char* dK = (char*)sK + (size_t)(p * 256 + wave * 64) * 16;
      char* dV = (char*)sVT + (size_t)(p * 256 + wave * 64) * 16;
      gload_lds16(qk + (rowbase + kv0 + r) * 2048 + 1024 + h * 64 + pb * 8, dK);
      gload_lds16(vtb + (size_t)r * 2048 + kv0 + pb * 8, dV);
    }
    __syncthreads();

    // swapped QK^T: S^T[kv][q] = mfma(K, Q); lane holds S[q=lr][kv=fr*16+4g+i]
    f32x4 sc[4] = {};
#pragma unroll
    for (int st = 0; st < 2; ++st)
#pragma unroll
      for (int fr = 0; fr < 4; ++fr) {
        const int pb = (g + 4 * st) ^ (lr & 7);
        const s16x8 ak = *(const s16x8*)&sK[(fr * 16 + lr) * 64 + pb * 8];
        sc[fr] = mfma16(ak, aq[st], sc[fr]);
      }

    // online softmax: one q-row per lane, reduce across the 4 g-groups
    float rmax = -1e30f;
#pragma unroll
    for (int fr = 0; fr < 4; ++fr)
#pragma unroll
      for (int i = 0; i < 4; ++i) rmax = fmaxf(rmax, sc[fr][i]);
    rmax = fmaxf(rmax, __shfl_xor(rmax, 16));
    rmax = fmaxf(rmax, __shfl_xor(rmax, 32));
    const float mnew = fmaxf(mrun, rmax * 0.125f);
    const float alpha = __expf(mrun - mnew);
    mrun = mnew;
    float rsum = 0.0f;
#pragma unroll
    for (int fr = 0; fr < 4; ++fr)
#pragma unroll
      for (int i = 0; i < 4; ++i) {
        const float pp = __expf(sc[fr][i] * 0.125f - mnew);
        sc[fr][i] = pp;
        rsum += pp;
      }
    rsum += __shfl_xor(rsum, 16);
    rsum += __shfl_xor(rsum, 32);
    lrun = lrun * alpha + rsum;
#pragma unroll
    for (int f2 = 0; f2 < 4; ++f2)
#pragma unroll
      for (int i = 0; i < 4; ++i) oa[f2][i] *= alpha;

    // P[q=lr][kv]: in-lane kv-contiguous -> vectorized b64 writes (per-wave LDS)
#pragma unroll
    for (int fr = 0; fr < 4; ++fr) {
      bf16x4 pk;
#pragma unroll
      for (int i = 0; i < 4; ++i) pk[i] = (bf16_t)sc[fr][i];
      *(bf16x4*)&sP[wave][lr * 72 + fr * 16 + 4 * g] = pk;
    }

    // PV: O^T = mfma(VT-frag, P-frag)
#pragma unroll
    for (int st = 0; st < 2; ++st) {
      const s16x8 pa = *(const s16x8*)&sP[wave][lr * 72 + st * 32 + g * 8];
#pragma unroll
      for (int f2 = 0; f2 < 4; ++f2) {
        const int pb = (g + 4 * st) ^ (lr & 7);
        const s16x8 va = *(const s16x8*)&sVT[(f2 * 16 + lr) * 64 + pb * 8];
        oa[f2] = mfma16(va, pa, oa[f2]);
      }
    }
  }

  const float rl = 1.0f / lrun;
#pragma unroll
  for (int f2 = 0; f2 < 4; ++f2) {
    bf16x4 ov;
#pragma unroll
    for (int i = 0; i < 4; ++i) ov[i] = (bf16_t)(oa[f2][i] * rl);
    *(bf16x4*)&O[(rowbase + q0w + lr) * 1024 + h * 64 + f2 * 16 + 4 * g] = ov;
  }
}

// ---------------- launch ----------------
extern "C" void kernel_launch(void* const* d_in, const int* in_sizes, int n_in,
                              void* d_out, int out_size, void* d_ws, size_t ws_size,
                              hipStream_t stream) {
  const float* x    = (const float*)d_in[0];
  const float* ln1w = (const float*)d_in[1];
  const float* ln1b = (const float*)d_in[2];
  const float* Wqkv = (const float*)d_in[3];
  const float* bqkv = (const float*)d_in[4];
  const float* Wo   = (const float*)d_in[5];
  const float* bo   = (const float*)d_in[6];
  const float* ln2w = (const float*)d_in[7];
  const float* ln2b = (const float*)d_in[8];
  const float* fc1w = (const float*)d_in[9];
  const float* fc1b = (const float*)d_in[10];
  const float* fc2w = (const float*)d_in[11];
  const float* fc2b = (const float*)d_in[12];

  const int M = 8192;

  char* ws = (char*)d_ws;
  size_t off = 0;
  auto alloc = [&](size_t bytes) {
    char* p = ws + off;
    off += (bytes + 255) & ~(size_t)255;
    return p;
  };
  // persistent weights (bf16, transposed)
  bf16_t* WqkvT = (bf16_t*)alloc((size_t)3072 * 1024 * 2);   // 6 MB
  bf16_t* WoT   = (bf16_t*)alloc((size_t)1024 * 1024 * 2);   // 2 MB
  bf16_t* fc1T  = (bf16_t*)alloc((size_t)4096 * 1024 * 2);   // 8 MB
  bf16_t* fc2T  = (bf16_t*)alloc((size_t)1024 * 4096 * 2);   // 8 MB
  // activations
  bf16_t* h1    = (bf16_t*)alloc((size_t)M * 1024 * 2);      // 16 MB (reused as h2)
  bf16_t* qkQK  = (bf16_t*)alloc((size_t)M * 2048 * 2);      // 32 MB (part 1 of 64 MB attn region)
  bf16_t* vTg   = (bf16_t*)alloc((size_t)M * 1024 * 2);      // 16 MB (part 2)
  bf16_t* attnO = (bf16_t*)alloc((size_t)M * 1024 * 2);      // 16 MB (part 3)
  float*  x2    = (float*)alloc((size_t)M * 1024 * 4);       // 32 MB
  // aliases: lifetimes disjoint in stream order
  bf16_t* h2   = h1;     // h1 dead after QKV GEMM
  bf16_t* gbuf = qkQK;   // qkQK/vTg dead after attn, attnO dead after o-proj
  if (off > ws_size) return;  // ~136 MB required

  const dim3 tb(32, 8);
  tcast_kernel<<<dim3(96, 32), tb, 0, stream>>>(Wqkv, WqkvT, 1024, 3072);
  tcast_kernel<<<dim3(32, 32), tb, 0, stream>>>(Wo, WoT, 1024, 1024);
  tcast_kernel<<<dim3(128, 32), tb, 0, stream>>>(fc1w, fc1T, 1024, 4096);
  tcast_kernel<<<dim3(32, 128), tb, 0, stream>>>(fc2w, fc2T, 4096, 1024);

  ln_kernel<<<M, 256, 0, stream>>>(x, ln1w, ln1b, h1);

  gemm128<3><<<dim3(64, 24), 256, 0, stream>>>(h1, WqkvT, bqkv, nullptr, qkQK, vTg, M, 3072, 1024);

  flash_attn2<<<dim3(32, 64), 256, 0, stream>>>(qkQK, vTg, attnO);

  gemm128<1><<<dim3(64, 8), 256, 0, stream>>>(attnO, WoT, bo, x, x2, nullptr, M, 1024, 1024);

  ln_kernel<<<M, 256, 0, stream>>>(x2, ln2w, ln2b, h2);

  gemm128<2><<<dim3(64, 32), 256, 0, stream>>>(h2, fc1T, fc1b, nullptr, gbuf, nullptr, M, 4096, 1024);

  gemm128<1><<<dim3(64, 8), 256, 0, stream>>>(gbuf, fc2T, fc2b, x2, (float*)d_out, nullptr, M, 1024, 4096);
}